// Round 3
// baseline (494.157 us; speedup 1.0000x reference)
//
#include <hip/hip_runtime.h>

// Persistent LSTM: N=4096, T=256, IN=2, E=64, H=128, OUT=2.
// 256 blocks x 1024 threads (16 waves), block b owns rows [16b,16b+16).
// K-SPLIT: wave (w8, kh) computes gates for units [16*w8,16*w8+16) over
// k-tiles {0,2,3} (kh=0, carries bias) or {1,4,5} (kh=1). Partial gate accs
// are summed via an LDS exchange (each side keeps 2 of its 4 C-rows, sends 2),
// so the elementwise is 2 cells/thread (14 trans) and per-wave weight
// fragments are 48 VGPR -> 4 waves/SIMD.
// A-buffer uses XOR swizzle slot^=(row&7) on 16B slots: conflict-free b128
// fragment reads. 3 rotating A-buffers keep embed 2 steps ahead (pre-issued
// MFMAs before the exchange barrier). y-proj k-split across the two w8==0
// waves, combined through Ybuf.

#define T_LEN 256
#define NROW  16

typedef __attribute__((ext_vector_type(8))) short short8;
typedef __attribute__((ext_vector_type(4))) float f32x4;
typedef __attribute__((ext_vector_type(2))) float f32x2;

__device__ __forceinline__ unsigned short f2bf(float f) {
  unsigned u = __builtin_bit_cast(unsigned, f);
  u += 0x7fffu + ((u >> 16) & 1u);           // RNE
  return (unsigned short)(u >> 16);
}
__device__ __forceinline__ f32x2 exp2v(f32x2 x) {
  return (f32x2){__builtin_amdgcn_exp2f(x[0]), __builtin_amdgcn_exp2f(x[1])};
}
__device__ __forceinline__ f32x2 rcpv(f32x2 x) {
  return (f32x2){__builtin_amdgcn_rcpf(x[0]), __builtin_amdgcn_rcpf(x[1])};
}

// fused LSTM cell on 2 rows: sig(x)=1/(1+2^(K1 x)), tanh=(1-2^(K2 x))/(1+2^(K2 x))
__device__ __forceinline__ f32x2 ewpair(f32x2 i, f32x2 f, f32x2 g, f32x2 o, f32x2& c) {
  const float K1 = -1.4426950408889634f, K2 = -2.8853900817779268f;
  f32x2 ei = exp2v(i * K1);
  f32x2 ef = exp2v(f * K1);
  f32x2 eg = exp2v(g * K2);
  f32x2 eo = exp2v(o * K1);
  f32x2 t1 = ei + 1.f, tf = ef + 1.f, t2 = eg + 1.f, t3 = 1.f - eg, to = eo + 1.f;
  f32x2 q1 = t1 * t2;
  f32x2 num = c * q1 + t3 * tf;
  f32x2 cn = num * rcpv(q1 * tf);
  c = cn;
  f32x2 cc = __builtin_elementwise_min(
      __builtin_elementwise_max(cn, (f32x2){-20.f, -20.f}), (f32x2){20.f, 20.f});
  f32x2 ec = exp2v(cc * K2);
  return (1.f - ec) * rcpv(to * (ec + 1.f));
}

__global__ __launch_bounds__(1024, 4) void lstm_persist(
    const float* __restrict__ x,    const float* __restrict__ W_in,
    const float* __restrict__ b_in, const float* __restrict__ W_ih,
    const float* __restrict__ W_hh, const float* __restrict__ b_ih,
    const float* __restrict__ b_hh, const float* __restrict__ W_out,
    const float* __restrict__ b_out, float* __restrict__ out)
{
  __shared__ __align__(16) float xsT[2 * T_LEN][NROW];            // 32 KB
  __shared__ __align__(16) unsigned short Abuf[3][NROW * 192];    // 18 KB, swizzled
  __shared__ __align__(16) float Xbuf[2][8][64 * 12];             // 48 KB exchange
  __shared__ __align__(16) float Ybuf[64 * 4];                    // 1 KB
  __shared__ float WinS[128];
  __shared__ float binS[64];

  const int tid = threadIdx.x;
  const int w   = tid >> 6;        // 0..15
  const int l   = tid & 63;
  const int l15 = l & 15;
  const int lq  = l >> 4;
  const int kh  = w >> 3;          // k-half
  const int w8  = w & 7;           // unit group
  const int u   = w8 * 16 + l15;

  // ---- stage x transposed ----
  const float* xg = x + (size_t)blockIdx.x * NROW * 2 * T_LEN;
  for (int i = tid; i < NROW * 2 * T_LEN / 4; i += 1024) {
    float4 v = ((const float4*)xg)[i];
    int fi = i * 4, r = fi >> 9, c0 = fi & 511;
    xsT[c0][r] = v.x; xsT[c0 + 1][r] = v.y; xsT[c0 + 2][r] = v.z; xsT[c0 + 3][r] = v.w;
  }
  if (tid < 128) WinS[tid] = W_in[tid];
  if (tid < 64)  binS[tid] = b_in[tid];

  // ---- k-tile assignment ----
  const int kt0 = kh ? 1 : 0;      // embed kt (pre-issue)
  const int ktA = kh ? 4 : 2;      // h kts (critical phase)
  const int ktB = kh ? 5 : 3;

  // ---- weight fragments (registers, bf16) ----
  short8 fb[4][3];
  float  bias4[4];
  #pragma unroll
  for (int g = 0; g < 4; ++g) {
    const int grow = g * 128 + u;
    bias4[g] = (kh == 0) ? (b_ih[grow] + b_hh[grow]) : 0.f;
    const int kts[3] = {kt0, ktA, ktB};
    #pragma unroll
    for (int j = 0; j < 3; ++j) {
      const int kk = kts[j] * 32 + lq * 8;
      const float* src = (kk < 64) ? (W_ih + grow * 64 + kk)
                                   : (W_hh + grow * 128 + (kk - 64));
      float4 lo = *(const float4*)src;
      float4 hi = *(const float4*)(src + 4);
      short8 f;
      f[0] = (short)f2bf(lo.x); f[1] = (short)f2bf(lo.y);
      f[2] = (short)f2bf(lo.z); f[3] = (short)f2bf(lo.w);
      f[4] = (short)f2bf(hi.x); f[5] = (short)f2bf(hi.y);
      f[6] = (short)f2bf(hi.z); f[7] = (short)f2bf(hi.w);
      fb[g][j] = f;
    }
  }
  // y-proj fragments: this wave's 2 h-kts, cols 0,1 = W_out rows
  short8 fbY[2];
  #pragma unroll
  for (int j = 0; j < 2; ++j) {
    short8 fy = {0, 0, 0, 0, 0, 0, 0, 0};
    const int kt = ktA + j;
    if (l15 < 2) {
      const float* src = W_out + l15 * 128 + (kt - 2) * 32 + lq * 8;
      #pragma unroll
      for (int e = 0; e < 8; ++e) fy[e] = (short)f2bf(src[e]);
    }
    fbY[j] = fy;
  }
  const float bout_r = (l15 < 2) ? b_out[l15] : 0.f;

  __syncthreads();  // xsT ready

  auto frag_read = [&](const unsigned short* buf, int kt) -> short8 {
    return *(const short8*)&buf[l15 * 192 + (((kt * 4 + lq) ^ (l15 & 7)) * 8)];
  };
  auto embed1 = [&](unsigned short* buf, int t) {
    const float x0 = xsT[2 * t][w], x1 = xsT[2 * t + 1][w];
    float v = fmaf(x1, WinS[2 * l + 1], fmaf(x0, WinS[2 * l], binS[l]));
    v = v > 0.f ? v : 0.f;
    buf[w * 192 + (((l >> 3) ^ (w & 7)) * 8) + (l & 7)] = f2bf(v);
  };
  auto hwrite = [&](unsigned short* buf, int r, float v) {
    buf[r * 192 + (((8 + (u >> 3)) ^ (r & 7)) * 8) + (u & 7)] = f2bf(v);
  };

  // zero h region of buf0 (1024 u32, one per thread); embeds e0->buf0, e1->buf1
  ((unsigned*)&Abuf[0][(tid >> 6) * 192 + 64])[tid & 63] = 0u;
  embed1(Abuf[0], 0);
  embed1(Abuf[1], 1);
  __syncthreads();

  // seed acc for t=0 (embed part + bias on kh0)
  f32x4 accA[4], accB[4];
  {
    const short8 a0 = frag_read(Abuf[0], kt0);
    #pragma unroll
    for (int g = 0; g < 4; ++g) {
      f32x4 s = (f32x4){bias4[g], bias4[g], bias4[g], bias4[g]};
      accA[g] = __builtin_amdgcn_mfma_f32_16x16x32_bf16(a0, fb[g][0], s, 0, 0, 0);
    }
  }

  f32x2 c01 = {0.f, 0.f};
  const size_t obase = (size_t)blockIdx.x * NROW * 2 * T_LEN;
  const int qa = kh ? 0 : 2;       // rows this side SENDS
  const int qk = kh ? 2 : 0;       // rows this side KEEPS
  const int r0 = lq * 4 + 2 * kh;  // first kept row

  auto step = [&](int t, unsigned short* bR, unsigned short* bW, unsigned short* bE,
                  f32x4 (&accC)[4], f32x4 (&accN)[4]) {
    const short8 ahA = frag_read(bR, ktA);
    const short8 ahB = frag_read(bR, ktB);
    #pragma unroll
    for (int g = 0; g < 4; ++g)
      accC[g] = __builtin_amdgcn_mfma_f32_16x16x32_bf16(ahA, fb[g][1], accC[g], 0, 0, 0);
    #pragma unroll
    for (int g = 0; g < 4; ++g)
      accC[g] = __builtin_amdgcn_mfma_f32_16x16x32_bf16(ahB, fb[g][2], accC[g], 0, 0, 0);

    // y_{t-1} partials (waves w8==0), k-split
    f32x4 accY;
    if (w8 == 0) {
      if (kh == 0) {
        const int tt = (t > 0) ? t - 1 : 0;
        #pragma unroll
        for (int q = 0; q < 4; ++q)
          accY[q] = (l15 < 2) ? (bout_r + xsT[2 * tt + l15][lq * 4 + q]) : 0.f;
      } else {
        accY = (f32x4){0.f, 0.f, 0.f, 0.f};
      }
      accY = __builtin_amdgcn_mfma_f32_16x16x32_bf16(ahA, fbY[0], accY, 0, 0, 0);
      accY = __builtin_amdgcn_mfma_f32_16x16x32_bf16(ahB, fbY[1], accY, 0, 0, 0);
      if (kh == 1) *(f32x4*)&Ybuf[l * 4] = accY;
    }

    // exchange write: send rows qa,qa+1 of all 4 gates
    {
      float* xb = &Xbuf[kh][w8][l * 12];
      *(f32x4*)xb       = (f32x4){accC[0][qa], accC[0][qa + 1], accC[1][qa], accC[1][qa + 1]};
      *(f32x4*)(xb + 4) = (f32x4){accC[2][qa], accC[2][qa + 1], accC[3][qa], accC[3][qa + 1]};
    }

    // pre-issue next step's embed MFMAs (bW embed resident since t-1)
    if (t + 1 < T_LEN) {
      const short8 a0 = frag_read(bW, kt0);
      #pragma unroll
      for (int g = 0; g < 4; ++g) {
        f32x4 s = (f32x4){bias4[g], bias4[g], bias4[g], bias4[g]};
        accN[g] = __builtin_amdgcn_mfma_f32_16x16x32_bf16(a0, fb[g][0], s, 0, 0, 0);
      }
    }

    __syncthreads();  // B1: exchange/Ybuf visible

    // EW on kept rows: add partner partials, fused LSTM cell, h -> bW
    {
      const float* xb = &Xbuf[kh ^ 1][w8][l * 12];
      const f32x4 p0 = *(const f32x4*)xb;
      const f32x4 p1 = *(const f32x4*)(xb + 4);
      f32x2 iv = {accC[0][qk] + p0[0], accC[0][qk + 1] + p0[1]};
      f32x2 fv = {accC[1][qk] + p0[2], accC[1][qk + 1] + p0[3]};
      f32x2 gv = {accC[2][qk] + p1[0], accC[2][qk + 1] + p1[1]};
      f32x2 ov = {accC[3][qk] + p1[2], accC[3][qk + 1] + p1[3]};
      f32x2 hv = ewpair(iv, fv, gv, ov, c01);
      hwrite(bW, r0,     hv[0]);
      hwrite(bW, r0 + 1, hv[1]);
    }

    // embed e_{t+2} -> bE (1 value/thread)
    if (t + 2 < T_LEN) embed1(bE, t + 2);

    // y_{t-1} combine + store (wave w8==0, kh==0)
    if (w8 == 0 && kh == 0 && t > 0) {
      const f32x4 py = *(const f32x4*)&Ybuf[l * 4];
      if (l15 < 2) {
        #pragma unroll
        for (int q = 0; q < 4; ++q)
          out[obase + (size_t)(lq * 4 + q) * (2 * T_LEN) + 2 * (t - 1) + l15] = accY[q] + py[q];
      }
    }

    __syncthreads();  // B2: bW h + bE embed complete
  };

  unsigned short* A0 = Abuf[0];
  unsigned short* A1 = Abuf[1];
  unsigned short* A2 = Abuf[2];

  for (int t = 0; t < 252; t += 6) {
    step(t + 0, A0, A1, A2, accA, accB);
    step(t + 1, A1, A2, A0, accB, accA);
    step(t + 2, A2, A0, A1, accA, accB);
    step(t + 3, A0, A1, A2, accB, accA);
    step(t + 4, A1, A2, A0, accA, accB);
    step(t + 5, A2, A0, A1, accB, accA);
  }
  step(252, A0, A1, A2, accA, accB);
  step(253, A1, A2, A0, accB, accA);
  step(254, A2, A0, A1, accA, accB);
  step(255, A0, A1, A2, accB, accA);

  // epilogue: y_255 from h_256 (in Abuf[1])
  f32x4 accYe = (f32x4){0.f, 0.f, 0.f, 0.f};
  if (w8 == 0) {
    const short8 ahA = frag_read(A1, ktA);
    const short8 ahB = frag_read(A1, ktB);
    if (kh == 0) {
      #pragma unroll
      for (int q = 0; q < 4; ++q)
        accYe[q] = (l15 < 2) ? (bout_r + xsT[2 * 255 + l15][lq * 4 + q]) : 0.f;
    }
    accYe = __builtin_amdgcn_mfma_f32_16x16x32_bf16(ahA, fbY[0], accYe, 0, 0, 0);
    accYe = __builtin_amdgcn_mfma_f32_16x16x32_bf16(ahB, fbY[1], accYe, 0, 0, 0);
    if (kh == 1) *(f32x4*)&Ybuf[l * 4] = accYe;
  }
  __syncthreads();
  if (w8 == 0 && kh == 0 && l15 < 2) {
    const f32x4 py = *(const f32x4*)&Ybuf[l * 4];
    #pragma unroll
    for (int q = 0; q < 4; ++q)
      out[obase + (size_t)(lq * 4 + q) * (2 * T_LEN) + 2 * 255 + l15] = accYe[q] + py[q];
  }
}

extern "C" void kernel_launch(void* const* d_in, const int* in_sizes, int n_in,
                              void* d_out, int out_size, void* d_ws, size_t ws_size,
                              hipStream_t stream) {
  const float* x     = (const float*)d_in[0];
  const float* W_in  = (const float*)d_in[1];
  const float* b_in  = (const float*)d_in[2];
  const float* W_ih  = (const float*)d_in[3];
  const float* W_hh  = (const float*)d_in[4];
  const float* b_ih  = (const float*)d_in[5];
  const float* b_hh  = (const float*)d_in[6];
  const float* W_out = (const float*)d_in[7];
  const float* b_out = (const float*)d_in[8];
  float* out = (float*)d_out;

  lstm_persist<<<dim3(256), dim3(1024), 0, stream>>>(
      x, W_in, b_in, W_ih, W_hh, b_ih, b_hh, W_out, b_out, out);
}